// Round 13
// baseline (146.709 us; speedup 1.0000x reference)
//
#include <hip/hip_runtime.h>
#include <math.h>

// Problem constants (from reference setup_inputs)
constexpr int B  = 8;
constexpr int C  = 256;
constexpr int Q  = 85;              // C/D; channel->dim: d = min(c/Q, 2)
constexpr int NS0 = 16384, NS1 = 4096, NS2 = 1024, NS3 = 256;
constexpr int PAR = NS1 + NS2 + NS3;        // parents, levels 0-2
constexpr int SLT = NS0 + NS1 + NS2;        // slots (= children), levels 0-2
constexpr int CH  = 512;                    // leaves per mega block
constexpr int NCH = NS0 / CH;               // 32 chunks
constexpr int MEGA_GRID = B * 3 * NCH;      // 768 blocks

// ---------------------------------------------------------------------------
// Single-dim sibling-group weight: group = 4 children at base (float view of
// dslot), dim d. Returns target child's weight and the sum over all 4.
// ---------------------------------------------------------------------------
__device__ __forceinline__ void sib1(const float* __restrict__ base, int d,
                                     int target, float& wt, float& zs) {
    float v0 = base[0 * 4 + d], v1 = base[1 * 4 + d];
    float v2 = base[2 * 4 + d], v3 = base[3 * 4 + d];
    int i0 = __float_as_int(base[0 * 4 + 3]);
    int i1 = __float_as_int(base[1 * 4 + 3]);
    int i2 = __float_as_int(base[2 * 4 + 3]);
    int i3 = __float_as_int(base[3 * 4 + 3]);
    float mx = fmaxf(fmaxf(v0, v1), fmaxf(v2, v3));
    float mn = fminf(fminf(v0, v1), fminf(v2, v3));
    float pos = fmaxf(mx, 0.f), neg = fminf(mn, 0.f);
    float w0 = 1.f - fabsf(v0) / (fabsf(v0 >= 0.f ? pos : neg) + 1e-6f);
    float w1 = 1.f - fabsf(v1) / (fabsf(v1 >= 0.f ? pos : neg) + 1e-6f);
    float w2 = 1.f - fabsf(v2) / (fabsf(v2 >= 0.f ? pos : neg) + 1e-6f);
    float w3 = 1.f - fabsf(v3) / (fabsf(v3 >= 0.f ? pos : neg) + 1e-6f);
    zs = w0 + w1 + w2 + w3;
    wt = 0.f;
    if (i0 == target) wt = w0;
    if (i1 == target) wt = w1;
    if (i2 == target) wt = w2;
    if (i3 == target) wt = w3;
}

// ---------------------------------------------------------------------------
// Kernel 1: fused inversion (levels 0-2) + level-3 weights + accum init.
//  y<3 : per-child slot assignment + delta -> dslot.
//        slot = atomicAdd(cnt)&3 is correct from ANY counter start value
//        (4 consecutive returns are distinct mod 4) -> no init pass needed.
//  y==3: blocks 0-7: level-3 weights (LDS tree reduction, one per batch);
//        block 8: zero accum (B*C floats) + grid counter (replay re-init).
// ---------------------------------------------------------------------------
__global__ void invert_fused_kernel(const int* __restrict__ idx0,
                                    const int* __restrict__ idx1,
                                    const int* __restrict__ idx2,
                                    const float* __restrict__ c0,
                                    const float* __restrict__ c1,
                                    const float* __restrict__ c2,
                                    const float* __restrict__ c3,
                                    const float* __restrict__ c4,
                                    unsigned* __restrict__ cnt,    // (B,PAR) no init needed
                                    float4*   __restrict__ dslot,  // (B,SLT)
                                    float*    __restrict__ w3,     // (B,256,3)
                                    float*    __restrict__ z4,     // (B,3)
                                    float*    __restrict__ accum,  // (B,C)
                                    unsigned* __restrict__ counter) {
    __shared__ float sm[3][256];
    __shared__ float sn[3][256];

    if (blockIdx.y == 3) {
        if (blockIdx.x == 8) {
            // zero accum + counter for this call (graph replays re-run this)
            int i = threadIdx.x;
            for (; i < B * C; i += 256) accum[i] = 0.f;
            if (threadIdx.x == 0) *counter = 0u;
            return;
        }
        if (blockIdx.x >= 8) return;
        // ---- level-3 weights (one block per batch) ----
        int b = blockIdx.x;
        int n = threadIdx.x;

        float pc0 = c4[b * 3 + 0], pc1 = c4[b * 3 + 1], pc2 = c4[b * 3 + 2];
        const float* cp = &c3[((size_t)(b * 256 + n)) * 3];
        float d0 = cp[0] - pc0, d1 = cp[1] - pc1, d2 = cp[2] - pc2;
        sm[0][n] = d0; sm[1][n] = d1; sm[2][n] = d2;
        sn[0][n] = d0; sn[1][n] = d1; sn[2][n] = d2;
        __syncthreads();
        for (int s = 128; s > 0; s >>= 1) {
            if (n < s) {
#pragma unroll
                for (int d = 0; d < 3; ++d) {
                    sm[d][n] = fmaxf(sm[d][n], sm[d][n + s]);
                    sn[d][n] = fminf(sn[d][n], sn[d][n + s]);
                }
            }
            __syncthreads();
        }
        float pos0 = fmaxf(sm[0][0], 0.f), pos1 = fmaxf(sm[1][0], 0.f), pos2 = fmaxf(sm[2][0], 0.f);
        float neg0 = fminf(sn[0][0], 0.f), neg1 = fminf(sn[1][0], 0.f), neg2 = fminf(sn[2][0], 0.f);
        __syncthreads();

        float w0 = 1.f - fabsf(d0) / (fabsf(d0 >= 0.f ? pos0 : neg0) + 1e-6f);
        float w1 = 1.f - fabsf(d1) / (fabsf(d1 >= 0.f ? pos1 : neg1) + 1e-6f);
        float w2 = 1.f - fabsf(d2) / (fabsf(d2 >= 0.f ? pos2 : neg2) + 1e-6f);
        float* wp = &w3[((size_t)(b * 256 + n)) * 3];
        wp[0] = w0; wp[1] = w1; wp[2] = w2;

        sm[0][n] = w0; sm[1][n] = w1; sm[2][n] = w2;
        __syncthreads();
        for (int s = 128; s > 0; s >>= 1) {
            if (n < s) {
#pragma unroll
                for (int d = 0; d < 3; ++d) sm[d][n] += sm[d][n + s];
            }
            __syncthreads();
        }
        if (n == 0) {
            z4[b * 3 + 0] = sm[0][0];
            z4[b * 3 + 1] = sm[1][0];
            z4[b * 3 + 2] = sm[2][0];
        }
        return;
    }

    // ---- levels 0-2 inversion ----
    int lvl = blockIdx.y;
    const int*   idx = (lvl == 0) ? idx0 : (lvl == 1 ? idx1 : idx2);
    const float* cc  = (lvl == 0) ? c0   : (lvl == 1 ? c1   : c2);
    const float* cn  = (lvl == 0) ? c1   : (lvl == 1 ? c2   : c3);
    int N  = (lvl == 0) ? NS0 : (lvl == 1 ? NS1 : NS2);
    int Nn = (lvl == 0) ? NS1 : (lvl == 1 ? NS2 : NS3);
    int cbase = (lvl == 0) ? 0 : (lvl == 1 ? NS1 : NS1 + NS2);
    int sbase = (lvl == 0) ? 0 : (lvl == 1 ? NS0 : NS0 + NS1);

    int t = blockIdx.x * blockDim.x + threadIdx.x;
    if (t >= B * N) return;
    int b = t / N;
    int n = t - b * N;
    int j = idx[t];
    int pj = b * Nn + j;

    unsigned o = atomicAdd(&cnt[(size_t)b * PAR + cbase + j], 1u);
    int slot = (int)(o & 3u);

    float4 dv;
    dv.x = cc[(size_t)t * 3 + 0] - cn[(size_t)pj * 3 + 0];
    dv.y = cc[(size_t)t * 3 + 1] - cn[(size_t)pj * 3 + 1];
    dv.z = cc[(size_t)t * 3 + 2] - cn[(size_t)pj * 3 + 2];
    dv.w = __int_as_float(n);
    dslot[((size_t)b * SLT + sbase + (size_t)j * 4) + slot] = dv;
}

// ---------------------------------------------------------------------------
// Kernel 2: MEGA. Block = (b, d, 512-leaf chunk); 768 blocks, 256 threads.
// Phase 1: per-leaf effective weight (dim d) via dslot chain -> LDS.
// Phase 2: stream x for the d-group's channels over the contiguous leaf
//          range (coalesced float4, x read exactly once), wave-reduce,
//          atomicAdd partial into accum[b][c].
// Tail:    last finished block applies cbrt and writes d_out.
// ---------------------------------------------------------------------------
__global__ __launch_bounds__(256)
void mega_kernel(const float* __restrict__ x,     // (B,C,NS0)
                 const int*   __restrict__ idx0,
                 const int*   __restrict__ idx1,
                 const int*   __restrict__ idx2,
                 const float4* __restrict__ dslot, // (B,SLT)
                 const float* __restrict__ w3,     // (B,256,3)
                 const float* __restrict__ z4,     // (B,3)
                 float*    __restrict__ accum,     // (B,C)
                 unsigned* __restrict__ counter,
                 float*    __restrict__ out,       // (B,C)
                 const float* __restrict__ p_arr) {
    __shared__ float Wl[CH];
    __shared__ int lastflag;
    int bi = blockIdx.x;
    int b = bi / (3 * NCH);
    int r = bi - b * (3 * NCH);
    int d = r / NCH;
    int chunk = r - d * NCH;
    int n0 = chunk * CH;
    int tid = threadIdx.x;

    float p = p_arr[0];
    bool p3 = (p == 3.0f);
    float z4v = z4[b * 3 + d];
    const float* ds = (const float*)dslot;
    const size_t dsb = (size_t)b * SLT * 4;   // float offset of batch base

    // ---- Phase 1: effective leaf weights for dim d, leaves [n0, n0+CH) ----
#pragma unroll
    for (int it = 0; it < CH / 256; ++it) {
        int li = tid + it * 256;
        int n = n0 + li;
        int j = idx0[(size_t)b * NS0 + n];
        float wt, zz;
        sib1(ds + dsb + (size_t)j * 16, d, n, wt, zz);
        int a2 = idx1[(size_t)b * NS1 + j];
        float w1t, z2;
        sib1(ds + dsb + (size_t)(NS0 + a2 * 4) * 4, d, j, w1t, z2);
        int a3 = idx2[(size_t)b * NS2 + a2];
        float w2t, z3;
        sib1(ds + dsb + (size_t)(NS0 + NS1 + a3 * 4) * 4, d, a2, w2t, z3);
        float w3v = w3[((size_t)b * 256 + a3) * 3 + d];
        Wl[li] = wt / (zz + 1e-6f) * w1t / (z2 + 1e-6f)
               * w2t / (z3 + 1e-6f) * w3v / (z4v + 1e-6f);
    }
    __syncthreads();

    // ---- Phase 2: stream channels of this d-group over the leaf range ----
    int lane = tid & 63;
    int cslot = tid >> 6;
    float4 wa = ((const float4*)Wl)[lane];        // leaves n0+4*lane..+3
    float4 wb = ((const float4*)Wl)[lane + 64];   // leaves n0+256+4*lane..+3
    int c_lo = d * Q;
    int c_hi = (d == 2) ? C : c_lo + Q;
    for (int c = c_lo + cslot; c < c_hi; c += 4) {
        const float4* xr = (const float4*)(x + ((size_t)(b * C + c)) * NS0 + n0);
        float4 xa = xr[lane];
        float4 xb = xr[lane + 64];
        float a0 = fmaxf(xa.x, 1e-6f), a1 = fmaxf(xa.y, 1e-6f);
        float a2v = fmaxf(xa.z, 1e-6f), a3v = fmaxf(xa.w, 1e-6f);
        float b0 = fmaxf(xb.x, 1e-6f), b1 = fmaxf(xb.y, 1e-6f);
        float b2 = fmaxf(xb.z, 1e-6f), b3 = fmaxf(xb.w, 1e-6f);
        float s0, s1, s2, s3, t0, t1, t2, t3;
        if (p3) {
            s0 = a0*a0*a0; s1 = a1*a1*a1; s2 = a2v*a2v*a2v; s3 = a3v*a3v*a3v;
            t0 = b0*b0*b0; t1 = b1*b1*b1; t2 = b2*b2*b2; t3 = b3*b3*b3;
        } else {
            s0 = powf(a0, p); s1 = powf(a1, p); s2 = powf(a2v, p); s3 = powf(a3v, p);
            t0 = powf(b0, p); t1 = powf(b1, p); t2 = powf(b2, p); t3 = powf(b3, p);
        }
        float acc = s0 * wa.x + s1 * wa.y + s2 * wa.z + s3 * wa.w
                  + t0 * wb.x + t1 * wb.y + t2 * wb.z + t3 * wb.w;
        // wave-64 reduction
        for (int o = 32; o > 0; o >>= 1) acc += __shfl_down(acc, o, 64);
        if (lane == 0) atomicAdd(&accum[b * C + c], acc);
    }

    // ---- Tail: last block finalizes ----
    __threadfence();
    if (tid == 0) {
        unsigned old = atomicAdd(counter, 1u);
        lastflag = (old == (unsigned)(gridDim.x - 1)) ? 1 : 0;
    }
    __syncthreads();
    if (lastflag) {
        for (int i = tid; i < B * C; i += 256) {
            float v = atomicAdd(&accum[i], 0.0f);   // coherent read
            out[i] = p3 ? cbrtf(v) : powf(v, 1.0f / p);
        }
    }
}

// ---------------------------------------------------------------------------
extern "C" void kernel_launch(void* const* d_in, const int* in_sizes, int n_in,
                              void* d_out, int out_size, void* d_ws, size_t ws_size,
                              hipStream_t stream) {
    const float* x      = (const float*)d_in[0];
    const int*   idx0   = (const int*)d_in[1];
    const int*   idx1   = (const int*)d_in[2];
    const int*   idx2   = (const int*)d_in[3];
    // d_in[4] (idx3) unused: level-3 parent is the single root node.
    const float* coords0 = (const float*)d_in[5];
    const float* coords1 = (const float*)d_in[6];
    const float* coords2 = (const float*)d_in[7];
    const float* coords3 = (const float*)d_in[8];
    const float* coords4 = (const float*)d_in[9];
    const float* p = (const float*)d_in[10];

    // Workspace carve-up (256B aligned)
    char* ws = (char*)d_ws;
    size_t off = 0;
    auto alloc = [&](size_t bytes) -> void* {
        off = (off + 255) & ~(size_t)255;
        void* r = ws + off;
        off += bytes;
        return r;
    };

    unsigned* cnt   = (unsigned*)alloc((size_t)B * PAR * sizeof(unsigned)); // never initialized (mod-4 trick)
    float4*   dslot = (float4*)alloc((size_t)B * SLT * sizeof(float4));
    float* w3    = (float*)alloc((size_t)B * NS3 * 3 * sizeof(float));
    float* z4    = (float*)alloc((size_t)B * 1   * 3 * sizeof(float));
    float* accum = (float*)alloc((size_t)B * C * sizeof(float));
    unsigned* counter = (unsigned*)alloc(256);

    dim3 ig((B * NS0 + 255) / 256, 4);     // y=0..2: invert levels; y=3: L3 weights + init
    invert_fused_kernel<<<ig, 256, 0, stream>>>(
        idx0, idx1, idx2, coords0, coords1, coords2, coords3, coords4,
        cnt, dslot, w3, z4, accum, counter);

    mega_kernel<<<MEGA_GRID, 256, 0, stream>>>(
        x, idx0, idx1, idx2, dslot, w3, z4, accum, counter, (float*)d_out, p);
}

// Round 14
// 50.316 us; speedup vs baseline: 2.9157x; 2.9157x over previous
//
#include <hip/hip_runtime.h>
#include <math.h>

// Problem constants (from reference setup_inputs)
constexpr int B  = 8;
constexpr int C  = 256;
constexpr int Q  = 85;              // C/D; channel->dim: d = min(c/Q, 2)
constexpr int NS0 = 16384, NS1 = 4096, NS2 = 1024, NS3 = 256;
constexpr int PAR = NS1 + NS2 + NS3;        // parents, levels 0-2
constexpr int SLT = NS0 + NS1 + NS2;        // slots (= children), levels 0-2

__device__ __forceinline__ int cdim(int c) {
    int d = c / Q;
    return d > 2 ? 2 : d;
}

// Sibling-group weight: given the 4 children of one parent (from dslot) and a
// target child node id, compute the target's per-dim weight and the per-dim
// sum over all 4 children.
__device__ __forceinline__ void sib_w(float4 c0, float4 c1, float4 c2, float4 c3,
                                      int target,
                                      float& wt0, float& wt1, float& wt2,
                                      float& zs0, float& zs1, float& zs2) {
    float mx0 = fmaxf(fmaxf(c0.x, c1.x), fmaxf(c2.x, c3.x));
    float mn0 = fminf(fminf(c0.x, c1.x), fminf(c2.x, c3.x));
    float mx1 = fmaxf(fmaxf(c0.y, c1.y), fmaxf(c2.y, c3.y));
    float mn1 = fminf(fminf(c0.y, c1.y), fminf(c2.y, c3.y));
    float mx2 = fmaxf(fmaxf(c0.z, c1.z), fmaxf(c2.z, c3.z));
    float mn2 = fminf(fminf(c0.z, c1.z), fminf(c2.z, c3.z));
    float pos0 = fmaxf(mx0, 0.f), neg0 = fminf(mn0, 0.f);
    float pos1 = fmaxf(mx1, 0.f), neg1 = fminf(mn1, 0.f);
    float pos2 = fmaxf(mx2, 0.f), neg2 = fminf(mn2, 0.f);

    zs0 = zs1 = zs2 = 0.f;
    wt0 = wt1 = wt2 = 0.f;
    float4 chs[4] = {c0, c1, c2, c3};
#pragma unroll
    for (int k = 0; k < 4; ++k) {
        float d0 = chs[k].x, d1 = chs[k].y, d2 = chs[k].z;
        int   n  = __float_as_int(chs[k].w);
        float wv0 = 1.f - fabsf(d0) / (fabsf(d0 >= 0.f ? pos0 : neg0) + 1e-6f);
        float wv1 = 1.f - fabsf(d1) / (fabsf(d1 >= 0.f ? pos1 : neg1) + 1e-6f);
        float wv2 = 1.f - fabsf(d2) / (fabsf(d2 >= 0.f ? pos2 : neg2) + 1e-6f);
        zs0 += wv0; zs1 += wv1; zs2 += wv2;
        if (n == target) { wt0 = wv0; wt1 = wv1; wt2 = wv2; }
    }
}

// ---------------------------------------------------------------------------
// Kernel 1: fused inversion (levels 0-2) + level-3 weights.  (R12, verified)
// ---------------------------------------------------------------------------
__global__ void invert_fused_kernel(const int* __restrict__ idx0,
                                    const int* __restrict__ idx1,
                                    const int* __restrict__ idx2,
                                    const float* __restrict__ c0,
                                    const float* __restrict__ c1,
                                    const float* __restrict__ c2,
                                    const float* __restrict__ c3,
                                    const float* __restrict__ c4,
                                    unsigned* __restrict__ cnt,    // (B,PAR) no init needed
                                    float4*   __restrict__ dslot,  // (B,SLT)
                                    float*    __restrict__ w3,     // (B,256,3)
                                    float*    __restrict__ z4) {   // (B,3)
    __shared__ float sm[3][256];
    __shared__ float sn[3][256];

    if (blockIdx.y == 3) {
        // ---- level-3 weights (one block per batch, 8 blocks used) ----
        if (blockIdx.x >= 8) return;
        int b = blockIdx.x;
        int n = threadIdx.x;

        float pc0 = c4[b * 3 + 0], pc1 = c4[b * 3 + 1], pc2 = c4[b * 3 + 2];
        const float* cp = &c3[((size_t)(b * 256 + n)) * 3];
        float d0 = cp[0] - pc0, d1 = cp[1] - pc1, d2 = cp[2] - pc2;
        sm[0][n] = d0; sm[1][n] = d1; sm[2][n] = d2;
        sn[0][n] = d0; sn[1][n] = d1; sn[2][n] = d2;
        __syncthreads();
        for (int s = 128; s > 0; s >>= 1) {
            if (n < s) {
#pragma unroll
                for (int d = 0; d < 3; ++d) {
                    sm[d][n] = fmaxf(sm[d][n], sm[d][n + s]);
                    sn[d][n] = fminf(sn[d][n], sn[d][n + s]);
                }
            }
            __syncthreads();
        }
        float pos0 = fmaxf(sm[0][0], 0.f), pos1 = fmaxf(sm[1][0], 0.f), pos2 = fmaxf(sm[2][0], 0.f);
        float neg0 = fminf(sn[0][0], 0.f), neg1 = fminf(sn[1][0], 0.f), neg2 = fminf(sn[2][0], 0.f);
        __syncthreads();

        float w0 = 1.f - fabsf(d0) / (fabsf(d0 >= 0.f ? pos0 : neg0) + 1e-6f);
        float w1 = 1.f - fabsf(d1) / (fabsf(d1 >= 0.f ? pos1 : neg1) + 1e-6f);
        float w2 = 1.f - fabsf(d2) / (fabsf(d2 >= 0.f ? pos2 : neg2) + 1e-6f);
        float* wp = &w3[((size_t)(b * 256 + n)) * 3];
        wp[0] = w0; wp[1] = w1; wp[2] = w2;

        sm[0][n] = w0; sm[1][n] = w1; sm[2][n] = w2;
        __syncthreads();
        for (int s = 128; s > 0; s >>= 1) {
            if (n < s) {
#pragma unroll
                for (int d = 0; d < 3; ++d) sm[d][n] += sm[d][n + s];
            }
            __syncthreads();
        }
        if (n == 0) {
            z4[b * 3 + 0] = sm[0][0];
            z4[b * 3 + 1] = sm[1][0];
            z4[b * 3 + 2] = sm[2][0];
        }
        return;
    }

    // ---- levels 0-2 inversion ----
    int lvl = blockIdx.y;
    const int*   idx = (lvl == 0) ? idx0 : (lvl == 1 ? idx1 : idx2);
    const float* cc  = (lvl == 0) ? c0   : (lvl == 1 ? c1   : c2);
    const float* cn  = (lvl == 0) ? c1   : (lvl == 1 ? c2   : c3);
    int N  = (lvl == 0) ? NS0 : (lvl == 1 ? NS1 : NS2);
    int Nn = (lvl == 0) ? NS1 : (lvl == 1 ? NS2 : NS3);
    int cbase = (lvl == 0) ? 0 : (lvl == 1 ? NS1 : NS1 + NS2);
    int sbase = (lvl == 0) ? 0 : (lvl == 1 ? NS0 : NS0 + NS1);

    int t = blockIdx.x * blockDim.x + threadIdx.x;
    if (t >= B * N) return;
    int b = t / N;
    int n = t - b * N;
    int j = idx[t];
    int pj = b * Nn + j;

    unsigned o = atomicAdd(&cnt[(size_t)b * PAR + cbase + j], 1u);
    int slot = (int)(o & 3u);

    float4 dv;
    dv.x = cc[(size_t)t * 3 + 0] - cn[(size_t)pj * 3 + 0];
    dv.y = cc[(size_t)t * 3 + 1] - cn[(size_t)pj * 3 + 1];
    dv.z = cc[(size_t)t * 3 + 2] - cn[(size_t)pj * 3 + 2];
    dv.w = __int_as_float(n);
    dslot[((size_t)b * SLT + sbase + (size_t)j * 4) + slot] = dv;
}

// ---------------------------------------------------------------------------
// Kernel 2: self-contained leaf-weight chain, one thread per LEVEL-1 node.
// (R12, verified: absmax 0)
// ---------------------------------------------------------------------------
__global__ void leafwn_kernel(const float4* __restrict__ dslot, // (B,SLT)
                              const int*   __restrict__ idx1,   // (B,NS1)
                              const int*   __restrict__ idx2,   // (B,NS2)
                              const float* __restrict__ w3,     // (B,256,3)
                              const float* __restrict__ z4,     // (B,3)
                              float* __restrict__ Wn) {         // (B,3,NS0)
    int t = blockIdx.x * blockDim.x + threadIdx.x;
    if (t >= B * NS1) return;
    int b = t / NS1;
    int j = t - b * NS1;

    // Own 4 leaves.
    const float4* dp0 = &dslot[(size_t)b * SLT + (size_t)j * 4];
    float4 l0 = dp0[0], l1 = dp0[1], l2 = dp0[2], l3 = dp0[3];

    float mx0 = fmaxf(fmaxf(l0.x, l1.x), fmaxf(l2.x, l3.x));
    float mn0 = fminf(fminf(l0.x, l1.x), fminf(l2.x, l3.x));
    float mx1 = fmaxf(fmaxf(l0.y, l1.y), fmaxf(l2.y, l3.y));
    float mn1 = fminf(fminf(l0.y, l1.y), fminf(l2.y, l3.y));
    float mx2 = fmaxf(fmaxf(l0.z, l1.z), fmaxf(l2.z, l3.z));
    float mn2 = fminf(fminf(l0.z, l1.z), fminf(l2.z, l3.z));
    float pos0 = fmaxf(mx0, 0.f), neg0 = fminf(mn0, 0.f);
    float pos1 = fmaxf(mx1, 0.f), neg1 = fminf(mn1, 0.f);
    float pos2 = fmaxf(mx2, 0.f), neg2 = fminf(mn2, 0.f);

    float wv0[4], wv1[4], wv2[4];
    int   nid[4];
    float zz0 = 0.f, zz1 = 0.f, zz2 = 0.f;
    float4 chs[4] = {l0, l1, l2, l3};
#pragma unroll
    for (int k = 0; k < 4; ++k) {
        float d0 = chs[k].x, d1 = chs[k].y, d2 = chs[k].z;
        nid[k] = __float_as_int(chs[k].w);
        wv0[k] = 1.f - fabsf(d0) / (fabsf(d0 >= 0.f ? pos0 : neg0) + 1e-6f);
        wv1[k] = 1.f - fabsf(d1) / (fabsf(d1 >= 0.f ? pos1 : neg1) + 1e-6f);
        wv2[k] = 1.f - fabsf(d2) / (fabsf(d2 >= 0.f ? pos2 : neg2) + 1e-6f);
        zz0 += wv0[k]; zz1 += wv1[k]; zz2 += wv2[k];
    }

    // Parent (level-1 sibling group under L2 node a2).
    int a2 = idx1[t];
    const float4* dp1 = &dslot[(size_t)b * SLT + NS0 + (size_t)a2 * 4];
    float w1t0, w1t1, w1t2, z20, z21, z22;
    sib_w(dp1[0], dp1[1], dp1[2], dp1[3], j, w1t0, w1t1, w1t2, z20, z21, z22);

    // Grandparent (level-2 sibling group under L3 node a3).
    int a3 = idx2[(size_t)b * NS2 + a2];
    const float4* dp2 = &dslot[(size_t)b * SLT + NS0 + NS1 + (size_t)a3 * 4];
    float w2t0, w2t1, w2t2, z30, z31, z32;
    sib_w(dp2[0], dp2[1], dp2[2], dp2[3], a2, w2t0, w2t1, w2t2, z30, z31, z32);

    const float* w3p = &w3[((size_t)b * 256 + a3) * 3];
    float U0 = w1t0 / (z20 + 1e-6f) * w2t0 / (z30 + 1e-6f) * w3p[0] / (z4[b * 3 + 0] + 1e-6f);
    float U1 = w1t1 / (z21 + 1e-6f) * w2t1 / (z31 + 1e-6f) * w3p[1] / (z4[b * 3 + 1] + 1e-6f);
    float U2 = w1t2 / (z22 + 1e-6f) * w2t2 / (z32 + 1e-6f) * w3p[2] / (z4[b * 3 + 2] + 1e-6f);

    float r0 = U0 / (zz0 + 1e-6f);
    float r1 = U1 / (zz1 + 1e-6f);
    float r2 = U2 / (zz2 + 1e-6f);

    float* Wb0 = Wn + ((size_t)(b * 3 + 0)) * NS0;
    float* Wb1 = Wn + ((size_t)(b * 3 + 1)) * NS0;
    float* Wb2 = Wn + ((size_t)(b * 3 + 2)) * NS0;
#pragma unroll
    for (int k = 0; k < 4; ++k) {
        int n = nid[k];
        Wb0[n] = wv0[k] * r0;
        Wb1[n] = wv1[k] * r1;
        Wb2[n] = wv2[k] * r2;
    }
}

// ---------------------------------------------------------------------------
// Kernel 3: weighted reduction over leaves, FOUR channels per block.
// out[b][c] = cbrt( sum_n max(x[b][c][n],eps)^3 * Wn[b][d(c)][n] )
// Block = (b, channel-quad). x still read exactly once (contiguous 4KB/iter
// per channel); the Wn row is shared across the quad (dup loads are L1-hits),
// cutting Wn re-read traffic from 134MB (one row per channel) to ~33MB.
// ---------------------------------------------------------------------------
__global__ __launch_bounds__(256)
void final_kernel(const float* __restrict__ x,   // (B,C,NS0)
                  const float* __restrict__ Wn,  // (B,3,NS0)
                  float* __restrict__ out,       // (B,C)
                  const float* __restrict__ p_arr) {
    __shared__ float4 sred[256];
    int bq = blockIdx.x;            // b*64 + quad
    int b = bq >> 6;
    int c0 = (bq & 63) * 4;
    float p = p_arr[0];
    bool p3 = (p == 3.0f);

    const float4* xr0 = (const float4*)(x + ((size_t)(b * C + c0 + 0)) * NS0);
    const float4* xr1 = (const float4*)(x + ((size_t)(b * C + c0 + 1)) * NS0);
    const float4* xr2 = (const float4*)(x + ((size_t)(b * C + c0 + 2)) * NS0);
    const float4* xr3 = (const float4*)(x + ((size_t)(b * C + c0 + 3)) * NS0);
    const float4* wr0 = (const float4*)(Wn + ((size_t)(b * 3 + cdim(c0 + 0))) * NS0);
    const float4* wr1 = (const float4*)(Wn + ((size_t)(b * 3 + cdim(c0 + 1))) * NS0);
    const float4* wr2 = (const float4*)(Wn + ((size_t)(b * 3 + cdim(c0 + 2))) * NS0);
    const float4* wr3 = (const float4*)(Wn + ((size_t)(b * 3 + cdim(c0 + 3))) * NS0);

    float a0 = 0.f, a1 = 0.f, a2 = 0.f, a3 = 0.f;
#pragma unroll 4
    for (int i = threadIdx.x; i < NS0 / 4; i += 256) {
        float4 w0 = wr0[i], w1 = wr1[i], w2 = wr2[i], w3 = wr3[i];
        float4 x0 = xr0[i], x1 = xr1[i], x2 = xr2[i], x3 = xr3[i];
        float v;
        if (p3) {
            v = fmaxf(x0.x, 1e-6f); a0 = fmaf(v*v*v, w0.x, a0);
            v = fmaxf(x0.y, 1e-6f); a0 = fmaf(v*v*v, w0.y, a0);
            v = fmaxf(x0.z, 1e-6f); a0 = fmaf(v*v*v, w0.z, a0);
            v = fmaxf(x0.w, 1e-6f); a0 = fmaf(v*v*v, w0.w, a0);
            v = fmaxf(x1.x, 1e-6f); a1 = fmaf(v*v*v, w1.x, a1);
            v = fmaxf(x1.y, 1e-6f); a1 = fmaf(v*v*v, w1.y, a1);
            v = fmaxf(x1.z, 1e-6f); a1 = fmaf(v*v*v, w1.z, a1);
            v = fmaxf(x1.w, 1e-6f); a1 = fmaf(v*v*v, w1.w, a1);
            v = fmaxf(x2.x, 1e-6f); a2 = fmaf(v*v*v, w2.x, a2);
            v = fmaxf(x2.y, 1e-6f); a2 = fmaf(v*v*v, w2.y, a2);
            v = fmaxf(x2.z, 1e-6f); a2 = fmaf(v*v*v, w2.z, a2);
            v = fmaxf(x2.w, 1e-6f); a2 = fmaf(v*v*v, w2.w, a2);
            v = fmaxf(x3.x, 1e-6f); a3 = fmaf(v*v*v, w3.x, a3);
            v = fmaxf(x3.y, 1e-6f); a3 = fmaf(v*v*v, w3.y, a3);
            v = fmaxf(x3.z, 1e-6f); a3 = fmaf(v*v*v, w3.z, a3);
            v = fmaxf(x3.w, 1e-6f); a3 = fmaf(v*v*v, w3.w, a3);
        } else {
            v = fmaxf(x0.x, 1e-6f); a0 = fmaf(powf(v, p), w0.x, a0);
            v = fmaxf(x0.y, 1e-6f); a0 = fmaf(powf(v, p), w0.y, a0);
            v = fmaxf(x0.z, 1e-6f); a0 = fmaf(powf(v, p), w0.z, a0);
            v = fmaxf(x0.w, 1e-6f); a0 = fmaf(powf(v, p), w0.w, a0);
            v = fmaxf(x1.x, 1e-6f); a1 = fmaf(powf(v, p), w1.x, a1);
            v = fmaxf(x1.y, 1e-6f); a1 = fmaf(powf(v, p), w1.y, a1);
            v = fmaxf(x1.z, 1e-6f); a1 = fmaf(powf(v, p), w1.z, a1);
            v = fmaxf(x1.w, 1e-6f); a1 = fmaf(powf(v, p), w1.w, a1);
            v = fmaxf(x2.x, 1e-6f); a2 = fmaf(powf(v, p), w2.x, a2);
            v = fmaxf(x2.y, 1e-6f); a2 = fmaf(powf(v, p), w2.y, a2);
            v = fmaxf(x2.z, 1e-6f); a2 = fmaf(powf(v, p), w2.z, a2);
            v = fmaxf(x2.w, 1e-6f); a2 = fmaf(powf(v, p), w2.w, a2);
            v = fmaxf(x3.x, 1e-6f); a3 = fmaf(powf(v, p), w3.x, a3);
            v = fmaxf(x3.y, 1e-6f); a3 = fmaf(powf(v, p), w3.y, a3);
            v = fmaxf(x3.z, 1e-6f); a3 = fmaf(powf(v, p), w3.z, a3);
            v = fmaxf(x3.w, 1e-6f); a3 = fmaf(powf(v, p), w3.w, a3);
        }
    }
    sred[threadIdx.x] = make_float4(a0, a1, a2, a3);
    __syncthreads();
    for (int s = 128; s > 0; s >>= 1) {
        if (threadIdx.x < s) {
            float4 o = sred[threadIdx.x + s];
            float4 m = sred[threadIdx.x];
            m.x += o.x; m.y += o.y; m.z += o.z; m.w += o.w;
            sred[threadIdx.x] = m;
        }
        __syncthreads();
    }
    if (threadIdx.x == 0) {
        float4 r = sred[0];
        float* op = &out[(size_t)b * C + c0];
        if (p3) {
            op[0] = cbrtf(r.x); op[1] = cbrtf(r.y);
            op[2] = cbrtf(r.z); op[3] = cbrtf(r.w);
        } else {
            float ip = 1.0f / p;
            op[0] = powf(r.x, ip); op[1] = powf(r.y, ip);
            op[2] = powf(r.z, ip); op[3] = powf(r.w, ip);
        }
    }
}

// ---------------------------------------------------------------------------
extern "C" void kernel_launch(void* const* d_in, const int* in_sizes, int n_in,
                              void* d_out, int out_size, void* d_ws, size_t ws_size,
                              hipStream_t stream) {
    const float* x      = (const float*)d_in[0];
    const int*   idx0   = (const int*)d_in[1];
    const int*   idx1   = (const int*)d_in[2];
    const int*   idx2   = (const int*)d_in[3];
    // d_in[4] (idx3) unused: level-3 parent is the single root node.
    const float* coords0 = (const float*)d_in[5];
    const float* coords1 = (const float*)d_in[6];
    const float* coords2 = (const float*)d_in[7];
    const float* coords3 = (const float*)d_in[8];
    const float* coords4 = (const float*)d_in[9];
    const float* p = (const float*)d_in[10];

    // Workspace carve-up (256B aligned)
    char* ws = (char*)d_ws;
    size_t off = 0;
    auto alloc = [&](size_t bytes) -> void* {
        off = (off + 255) & ~(size_t)255;
        void* r = ws + off;
        off += bytes;
        return r;
    };

    unsigned* cnt  = (unsigned*)alloc((size_t)B * PAR * sizeof(unsigned)); // never initialized (mod-4 trick)
    float4*  dslot = (float4*)alloc((size_t)B * SLT * sizeof(float4));
    float* w3 = (float*)alloc((size_t)B * NS3 * 3 * sizeof(float));
    float* z4 = (float*)alloc((size_t)B * 1   * 3 * sizeof(float));
    float* Wn = (float*)alloc((size_t)B * 3 * NS0 * sizeof(float));

    dim3 ig((B * NS0 + 255) / 256, 4);     // y=0..2: invert levels; y=3: level-3 weights
    invert_fused_kernel<<<ig, 256, 0, stream>>>(
        idx0, idx1, idx2, coords0, coords1, coords2, coords3, coords4,
        cnt, dslot, w3, z4);

    leafwn_kernel<<<(B * NS1 + 255) / 256, 256, 0, stream>>>(
        dslot, idx1, idx2, w3, z4, Wn);

    final_kernel<<<B * (C / 4), 256, 0, stream>>>(x, Wn, (float*)d_out, p);
}